// Round 2
// baseline (562.824 us; speedup 1.0000x reference)
//
#include <hip/hip_runtime.h>

#define BB 128
#define TT 3000
#define CC 64
#define LL 128
// S = 2L+1 = 257
#define NEG (-1e30f)
#define LOG2E 1.4426950408889634f
#define LN2f 0.6931471805599453f
#define CH 32                       // frames per LDS chunk
#define NCHUNK ((TT + CH - 1) / CH) // 94

__device__ __forceinline__ float fexp2(float x) { return __builtin_amdgcn_exp2f(x); }
__device__ __forceinline__ float flog2(float x) { return __builtin_amdgcn_logf(x); }

// base-2 logsumexp of two base-2 log-domain values
__device__ __forceinline__ float lse2(float x, float y) {
    float m = fmaxf(x, y);
    float d = x - y;
    float e = fexp2(-fabsf(d));
    return m + flog2(1.0f + e);
}
// base-2 logsumexp of three
__device__ __forceinline__ float lse3(float x, float y, float z) {
    float m = fmaxf(fmaxf(x, y), z);
    float s = fexp2(x - m) + fexp2(y - m) + fexp2(z - m);
    return m + flog2(s);
}

// Kernel 1: natural-log softmax normalizer per (b,t) row. One wave per row.
__global__ __launch_bounds__(256) void lse_kernel(const float* __restrict__ in,
                                                  float* __restrict__ lse) {
    int wid = (blockIdx.x * 256 + threadIdx.x) >> 6;   // row id = b*T + t
    int lane = threadIdx.x & 63;
    if (wid >= BB * TT) return;
    float x = in[(size_t)wid * CC + lane];
    float m = x;
    #pragma unroll
    for (int d = 32; d >= 1; d >>= 1) m = fmaxf(m, __shfl_xor(m, d, 64));
    float s = fexp2((x - m) * LOG2E);
    #pragma unroll
    for (int d = 32; d >= 1; d >>= 1) s += __shfl_xor(s, d, 64);
    if (lane == 0) lse[wid] = m + flog2(s) * LN2f;
}

// Kernel 2: CTC forward scan, one wave per batch element.
// Lane l owns states 4l..4l+3; lane 63 additionally owns state 256.
// Alphas kept in base-2 log domain on UNNORMALIZED logits.
__global__ __launch_bounds__(64) void scan_kernel(const float* __restrict__ in,
                                                  const int* __restrict__ tgt,
                                                  float* __restrict__ ll2out) {
    __shared__ float4 buf[2][CH * 16];  // CH frames * 64 floats, double buffered
    int b = blockIdx.x;
    int lane = threadIdx.x;
    const float4* gp = reinterpret_cast<const float4*>(in + (size_t)b * TT * CC);
    int t0 = tgt[b * LL + 2 * lane];      // channel for odd state 4l+1
    int t1 = tgt[b * LL + 2 * lane + 1];  // channel for odd state 4l+3

    // prologue: stage chunk 0
    float4 r[8];
    #pragma unroll
    for (int i = 0; i < 8; ++i) r[i] = gp[i * 64 + lane];
    #pragma unroll
    for (int i = 0; i < 8; ++i) buf[0][i * 64 + lane] = r[i];
    __syncthreads();

    float a0, a1, a2 = NEG, a3 = NEG, a4 = NEG;
    {   // t = 0 init: alpha[0]=em(blank), alpha[1]=em(target0), rest NEG
        const float* f = reinterpret_cast<const float*>(&buf[0][0]);
        float emB = f[63] * LOG2E;
        float em1 = f[t0] * LOG2E;
        a0 = (lane == 0) ? emB : NEG;
        a1 = (lane == 0) ? em1 : NEG;
    }

    for (int c = 0; c < NCHUNK; ++c) {
        int p = c & 1;
        // issue next-chunk global loads (latency hides under this chunk's compute)
        if (c + 1 < NCHUNK) {
            int base = (c + 1) * CH * 16;  // float4 index
            #pragma unroll
            for (int i = 0; i < 8; ++i) {
                int idx = base + i * 64 + lane;
                if (idx >= TT * 16) idx = TT * 16 - 1;  // clamp tail (unused data)
                r[i] = gp[idx];
            }
        }
        const float* fb = reinterpret_cast<const float*>(&buf[p][0]);
        int jstart = (c == 0) ? 1 : 0;
        int jend = (c * CH + CH <= TT) ? CH : (TT - c * CH);
        #pragma unroll 4
        for (int j = jstart; j < jend; ++j) {
            const float* f = fb + j * 64;
            float emB = f[63] * LOG2E;   // broadcast read (blank channel)
            float em1 = f[t0] * LOG2E;   // random reads
            float em3 = f[t1] * LOG2E;
            float p3 = __shfl_up(a3, 1, 64);   // prev lane's state 4l-1
            if (lane == 0) p3 = NEG;
            // even s=4l   : no skip -> lse2(alpha[s], alpha[s-1])
            // odd  s=4l+1 : skip    -> lse3(alpha[s], alpha[s-1], alpha[s-2])
            float n0 = emB + lse2(a0, p3);
            float n1 = em1 + lse3(a1, a0, p3);
            float n2 = emB + lse2(a2, a1);
            float n3 = em3 + lse3(a3, a2, a1);
            float n4 = emB + lse2(a4, a3);   // state 256 (only lane 63 meaningful)
            a0 = n0; a1 = n1; a2 = n2; a3 = n3; a4 = n4;
        }
        // stage next chunk into the other buffer
        if (c + 1 < NCHUNK) {
            #pragma unroll
            for (int i = 0; i < 8; ++i) buf[p ^ 1][i * 64 + lane] = r[i];
        }
        __syncthreads();  // single wave: just orders LDS writes before next reads
    }
    // accepting states 255 (lane63 a3) and 256 (lane63 a4)
    if (lane == 63) ll2out[b] = lse2(a3, a4);
}

// Kernel 3: per-batch loss_b = sum_t lse_nat[b,t] - ll2[b]*ln2
__global__ __launch_bounds__(256) void bsum_kernel(const float* __restrict__ lse,
                                                   const float* __restrict__ ll2,
                                                   float* __restrict__ lossb) {
    __shared__ float red[256];
    int b = blockIdx.x;
    float s = 0.f;
    for (int i = threadIdx.x; i < TT; i += 256) s += lse[(size_t)b * TT + i];
    red[threadIdx.x] = s;
    __syncthreads();
    #pragma unroll
    for (int w = 128; w >= 1; w >>= 1) {
        if (threadIdx.x < w) red[threadIdx.x] += red[threadIdx.x + w];
        __syncthreads();
    }
    if (threadIdx.x == 0) lossb[b] = red[0] - ll2[b] * LN2f;
}

// Kernel 4: mean over batch
__global__ __launch_bounds__(64) void final_kernel(const float* __restrict__ lossb,
                                                   float* __restrict__ out) {
    int lane = threadIdx.x;
    float v = lossb[lane] + lossb[lane + 64];
    #pragma unroll
    for (int d = 32; d >= 1; d >>= 1) v += __shfl_xor(v, d, 64);
    if (lane == 0) out[0] = v / (float)BB;
}

extern "C" void kernel_launch(void* const* d_in, const int* in_sizes, int n_in,
                              void* d_out, int out_size, void* d_ws, size_t ws_size,
                              hipStream_t stream) {
    const float* in = (const float*)d_in[0];
    const int* tg = (const int*)d_in[1];
    float* out = (float*)d_out;
    float* lse = (float*)d_ws;                 // B*T floats
    float* ll2 = lse + (size_t)BB * TT;        // B floats
    float* lossb = ll2 + BB;                   // B floats

    hipLaunchKernelGGL(scan_kernel, dim3(BB), dim3(64), 0, stream, in, tg, ll2);
    hipLaunchKernelGGL(lse_kernel, dim3((BB * TT) / 4), dim3(256), 0, stream, in, lse);
    hipLaunchKernelGGL(bsum_kernel, dim3(BB), dim3(256), 0, stream, lse, ll2, lossb);
    hipLaunchKernelGGL(final_kernel, dim3(1), dim3(64), 0, stream, lossb, out);
}

// Round 3
// 492.334 us; speedup vs baseline: 1.1432x; 1.1432x over previous
//
#include <hip/hip_runtime.h>

#define BB 128
#define TT 3000
#define CC 64
#define LL 128
// S = 2L+1 = 257
#define NEG (-1e30f)
#define LOG2E 1.4426950408889634f
#define LN2f 0.6931471805599453f
#define CH 24                        // frames per LDS chunk; 3000 = 125 * 24 exactly
#define NCHUNK 125

__device__ __forceinline__ float fexp2(float x) { return __builtin_amdgcn_exp2f(x); }
__device__ __forceinline__ float flog2(float x) { return __builtin_amdgcn_logf(x); }

// base-2 logsumexp of two base-2 log-domain values
__device__ __forceinline__ float lse2(float x, float y) {
    float m = fmaxf(x, y);
    float d = x - y;
    float e = fexp2(-fabsf(d));      // folds to v_exp_f32 with -|.| modifier
    return m + flog2(1.0f + e);
}
// lse2 + add0, with add0 folded onto the (early) max path:
// chain from late input y: sub -> exp -> add -> log -> add  (~28 cy)
__device__ __forceinline__ float lse2e(float x, float y, float add0) {
    float m = fmaxf(x, y) + add0;
    float d = x - y;
    float e = fexp2(-fabsf(d));
    return m + flog2(1.0f + e);
}

// lane l gets lane l-1's value via DPP wave_shr:1 (VALU, no LDS round trip).
// Lanes with no valid source (lane 0) keep `old` = NEG.
__device__ __forceinline__ float shr1_neg(float x) {
    int r = __builtin_amdgcn_update_dpp(__float_as_int(NEG), __float_as_int(x),
                                        0x138 /*wave_shr:1*/, 0xF, 0xF, false);
    return __int_as_float(r);
}

// Kernel 1: natural-log softmax normalizer per (b,t) row. One wave per row.
__global__ __launch_bounds__(256) void lse_kernel(const float* __restrict__ in,
                                                  float* __restrict__ lse) {
    int wid = (blockIdx.x * 256 + threadIdx.x) >> 6;   // row id = b*T + t
    int lane = threadIdx.x & 63;
    if (wid >= BB * TT) return;
    float x = in[(size_t)wid * CC + lane];
    float m = x;
    #pragma unroll
    for (int d = 32; d >= 1; d >>= 1) m = fmaxf(m, __shfl_xor(m, d, 64));
    float s = fexp2((x - m) * LOG2E);
    #pragma unroll
    for (int d = 32; d >= 1; d >>= 1) s += __shfl_xor(s, d, 64);
    if (lane == 0) lse[wid] = m + flog2(s) * LN2f;
}

// Kernel 2: CTC forward scan, one wave per batch element.
// Lane l owns states 4l..4l+3 (+ state 256 tracked as a4; for l<63 a4 duplicates
// lane l+1's a0 harmlessly). Alphas in base-2 log domain on UNNORMALIZED logits.
__global__ __launch_bounds__(64) void scan_kernel(const float* __restrict__ in,
                                                  const int* __restrict__ tgt,
                                                  float* __restrict__ ll2out) {
    __shared__ float4 buf[2][CH * 16];  // CH frames * 64 floats, double buffered
    int b = blockIdx.x;
    int lane = threadIdx.x;
    const float4* gp = reinterpret_cast<const float4*>(in + (size_t)b * TT * CC);
    int t0 = tgt[b * LL + 2 * lane];      // channel for odd state 4l+1
    int t1 = tgt[b * LL + 2 * lane + 1];  // channel for odd state 4l+3

    // prologue: stage chunk 0
    float4 r[6];
    #pragma unroll
    for (int i = 0; i < 6; ++i) r[i] = gp[i * 64 + lane];
    #pragma unroll
    for (int i = 0; i < 6; ++i) buf[0][i * 64 + lane] = r[i];
    __syncthreads();

    float a0, a1, a2 = NEG, a3 = NEG, a4 = NEG;
    {   // t = 0 init
        const float* f = reinterpret_cast<const float*>(&buf[0][0]);
        float emB = f[63] * LOG2E;
        float em1 = f[t0] * LOG2E;
        a0 = (lane == 0) ? emB : NEG;
        a1 = (lane == 0) ? em1 : NEG;
    }
    float u01 = lse2(a1, a0);   // precomputed combine for n1
    float v23 = lse2(a3, a2);   // precomputed combine for n3

    for (int c = 0; c < NCHUNK; ++c) {
        int p = c & 1;
        // issue next-chunk global loads (latency hides under this chunk's compute)
        if (c + 1 < NCHUNK) {
            const float4* src = gp + (size_t)(c + 1) * CH * 16;
            #pragma unroll
            for (int i = 0; i < 6; ++i) r[i] = src[i * 64 + lane];
        }
        const float* fb = reinterpret_cast<const float*>(&buf[p][0]);
        #pragma unroll
        for (int j = 0; j < CH; ++j) {
            if (j == 0) { if (c == 0) continue; }  // t=0 already consumed by init
            const float* f = fb + j * 64;
            float emB = f[63] * LOG2E;   // broadcast read (blank channel)
            float em1 = f[t0] * LOG2E;   // random-bank reads, off the serial chain
            float em3 = f[t1] * LOG2E;
            float p3 = shr1_neg(a3);     // prev lane's state 4l-1, VALU-speed
            // cross-lane critical cycle: p3 -> n1 -> (next step) n3 -> dpp
            float n1 = lse2e(u01, p3, em1);
            float n0 = lse2e(a0, p3, emB);
            float n2 = lse2e(a2, a1, emB);
            float n3 = lse2e(v23, a1, em3);
            float n4 = lse2e(a4, a3, emB);
            // prep combines for next step (off the p3 cycle)
            u01 = lse2(n1, n0);
            v23 = lse2(n3, n2);
            a0 = n0; a1 = n1; a2 = n2; a3 = n3; a4 = n4;
        }
        if (c + 1 < NCHUNK) {
            #pragma unroll
            for (int i = 0; i < 6; ++i) buf[p ^ 1][i * 64 + lane] = r[i];
        }
        __syncthreads();  // single wave: orders LDS writes before next reads
    }
    // accepting states 255 (lane63 a3) and 256 (lane63 a4)
    if (lane == 63) ll2out[b] = lse2(a3, a4);
}

// Kernel 3: per-batch loss_b = sum_t lse_nat[b,t] - ll2[b]*ln2
__global__ __launch_bounds__(256) void bsum_kernel(const float* __restrict__ lse,
                                                   const float* __restrict__ ll2,
                                                   float* __restrict__ lossb) {
    __shared__ float red[256];
    int b = blockIdx.x;
    float s = 0.f;
    for (int i = threadIdx.x; i < TT; i += 256) s += lse[(size_t)b * TT + i];
    red[threadIdx.x] = s;
    __syncthreads();
    #pragma unroll
    for (int w = 128; w >= 1; w >>= 1) {
        if (threadIdx.x < w) red[threadIdx.x] += red[threadIdx.x + w];
        __syncthreads();
    }
    if (threadIdx.x == 0) lossb[b] = red[0] - ll2[b] * LN2f;
}

// Kernel 4: mean over batch
__global__ __launch_bounds__(64) void final_kernel(const float* __restrict__ lossb,
                                                   float* __restrict__ out) {
    int lane = threadIdx.x;
    float v = lossb[lane] + lossb[lane + 64];
    #pragma unroll
    for (int d = 32; d >= 1; d >>= 1) v += __shfl_xor(v, d, 64);
    if (lane == 0) out[0] = v / (float)BB;
}

extern "C" void kernel_launch(void* const* d_in, const int* in_sizes, int n_in,
                              void* d_out, int out_size, void* d_ws, size_t ws_size,
                              hipStream_t stream) {
    const float* in = (const float*)d_in[0];
    const int* tg = (const int*)d_in[1];
    float* out = (float*)d_out;
    float* lse = (float*)d_ws;                 // B*T floats
    float* ll2 = lse + (size_t)BB * TT;        // B floats
    float* lossb = ll2 + BB;                   // B floats

    hipLaunchKernelGGL(scan_kernel, dim3(BB), dim3(64), 0, stream, in, tg, ll2);
    hipLaunchKernelGGL(lse_kernel, dim3((BB * TT) / 4), dim3(256), 0, stream, in, lse);
    hipLaunchKernelGGL(bsum_kernel, dim3(BB), dim3(256), 0, stream, lse, ll2, lossb);
    hipLaunchKernelGGL(final_kernel, dim3(1), dim3(64), 0, stream, lossb, out);
}

// Round 4
// 395.787 us; speedup vs baseline: 1.4220x; 1.2439x over previous
//
#include <hip/hip_runtime.h>

#define BB 128
#define TT 3000
#define CC 64
#define LL 128
// S = 2L+1 = 257
#define NEG (-1e30f)
#define LOG2E 1.4426950408889634f
#define LN2f 0.6931471805599453f
#define CH 12                 // frames per register chunk; 3000 = 250 * 12
#define NCHUNK 250
#define LSE_BLOCKS 1024       // extra blocks doing the softmax-normalizer pass

__device__ __forceinline__ float fexp2(float x) { return __builtin_amdgcn_exp2f(x); }
__device__ __forceinline__ float flog2(float x) { return __builtin_amdgcn_logf(x); }

// base-2 logsumexp of two base-2 log-domain values
__device__ __forceinline__ float lse2(float x, float y) {
    float m = fmaxf(x, y);
    float e = fexp2(-fabsf(x - y));          // v_exp_f32 with -|.| src modifier
    return m + flog2(1.0f + e);
}
// base-2 logsumexp of three
__device__ __forceinline__ float lse3(float x, float y, float z) {
    float m = fmaxf(fmaxf(x, y), z);
    float s = fexp2(x - m) + fexp2(y - m) + fexp2(z - m);
    return m + flog2(s);
}
// lane l gets lane l-1's value (lane 0 gets NEG) via DPP wave_shr:1 — VALU speed
__device__ __forceinline__ float shr1_neg(float x) {
    int r = __builtin_amdgcn_update_dpp(__float_as_int(NEG), __float_as_int(x),
                                        0x138 /*wave_shr:1*/, 0xF, 0xF, false);
    return __int_as_float(r);
}

// Fused kernel.
// Blocks 0..BB-1   : CTC forward scan for batch b (1 wave; emissions gathered
//                    from global directly into double-buffered register arrays).
// Blocks BB..      : per-(b,t)-row natural-log softmax normalizer (runs
//                    concurrently on otherwise-idle CUs).
__global__ __launch_bounds__(256) void fused_kernel(const float* __restrict__ in,
                                                    const int* __restrict__ tgt,
                                                    float* __restrict__ lse,
                                                    float* __restrict__ ll2) {
    if (blockIdx.x < BB) {
        if (threadIdx.x >= 64) return;       // scan uses wave 0 only
        __builtin_amdgcn_s_setprio(1);       // protect issue slots from lse waves
        int b = blockIdx.x;
        int lane = threadIdx.x;
        const float* fb = in + (size_t)b * TT * CC;
        int t0 = tgt[b * LL + 2 * lane];     // channel for odd state 4l+1
        int t1 = tgt[b * LL + 2 * lane + 1]; // channel for odd state 4l+3

        // double-buffered per-chunk emission registers (static indices only)
        float eA1[CH], eA3[CH], eAB[CH];
        float eB1[CH], eB3[CH], eBB[CH];

        // virtual pre-t=0 state: one uniform step then produces correct alpha_0
        float a0 = (lane == 0) ? 0.f : NEG;
        float a1 = NEG, a2 = NEG, a3 = NEG, a4 = NEG;

#define LOADC(S, c) { const float* bp = fb + (size_t)(c) * CH * CC;              \
        _Pragma("unroll") for (int j = 0; j < CH; ++j) {                         \
            e##S##1[j] = bp[j * CC + t0];                                        \
            e##S##3[j] = bp[j * CC + t1];                                        \
            e##S##B[j] = bp[j * CC + 63]; } }

#define STEPC(S) {                                                               \
        _Pragma("unroll") for (int j = 0; j < CH; ++j) {                         \
            float emB = e##S##B[j] * LOG2E;                                      \
            float em1 = e##S##1[j] * LOG2E;                                      \
            float em3 = e##S##3[j] * LOG2E;                                      \
            float p3 = shr1_neg(a3);                                             \
            float n0 = emB + lse2(a0, p3);                                       \
            float n1 = em1 + lse3(a1, a0, p3);                                   \
            float n2 = emB + lse2(a2, a1);                                       \
            float n3 = em3 + lse3(a3, a2, a1);                                   \
            float n4 = emB + lse2(a4, a3);                                       \
            a0 = n0; a1 = n1; a2 = n2; a3 = n3; a4 = n4; } }

        LOADC(A, 0);
        for (int c = 0; c < NCHUNK - 2; c += 2) {
            LOADC(B, c + 1);      // issue next chunk's gathers
            STEPC(A);             // compute current chunk from registers
            LOADC(A, c + 2);
            STEPC(B);
        }
        LOADC(B, NCHUNK - 1);
        STEPC(A);                 // chunk 248
        STEPC(B);                 // chunk 249
        // accepting states 255 (lane63 a3) and 256 (lane63 a4)
        if (lane == 63) ll2[b] = lse2(a3, a4);
        return;
    }
    // ---- softmax normalizer: one wave per (b,t) row, grid-strided ----
    int w = (blockIdx.x - BB) * 4 + (threadIdx.x >> 6);
    int lane = threadIdx.x & 63;
    const int stride = LSE_BLOCKS * 4;
    for (int row = w; row < BB * TT; row += stride) {
        float x = in[(size_t)row * CC + lane];
        float m = x;
        #pragma unroll
        for (int d = 32; d >= 1; d >>= 1) m = fmaxf(m, __shfl_xor(m, d, 64));
        float s = fexp2((x - m) * LOG2E);
        #pragma unroll
        for (int d = 32; d >= 1; d >>= 1) s += __shfl_xor(s, d, 64);
        if (lane == 0) lse[row] = m + flog2(s) * LN2f;
    }
}

// per-batch loss_b = sum_t lse_nat[b,t] - ll2[b]*ln2
__global__ __launch_bounds__(256) void bsum_kernel(const float* __restrict__ lse,
                                                   const float* __restrict__ ll2,
                                                   float* __restrict__ lossb) {
    __shared__ float red[256];
    int b = blockIdx.x;
    float s = 0.f;
    for (int i = threadIdx.x; i < TT; i += 256) s += lse[(size_t)b * TT + i];
    red[threadIdx.x] = s;
    __syncthreads();
    #pragma unroll
    for (int w = 128; w >= 1; w >>= 1) {
        if (threadIdx.x < w) red[threadIdx.x] += red[threadIdx.x + w];
        __syncthreads();
    }
    if (threadIdx.x == 0) lossb[b] = red[0] - ll2[b] * LN2f;
}

// mean over batch
__global__ __launch_bounds__(64) void final_kernel(const float* __restrict__ lossb,
                                                   float* __restrict__ out) {
    int lane = threadIdx.x;
    float v = lossb[lane] + lossb[lane + 64];
    #pragma unroll
    for (int d = 32; d >= 1; d >>= 1) v += __shfl_xor(v, d, 64);
    if (lane == 0) out[0] = v / (float)BB;
}

extern "C" void kernel_launch(void* const* d_in, const int* in_sizes, int n_in,
                              void* d_out, int out_size, void* d_ws, size_t ws_size,
                              hipStream_t stream) {
    const float* in = (const float*)d_in[0];
    const int* tg = (const int*)d_in[1];
    float* out = (float*)d_out;
    float* lse = (float*)d_ws;                 // B*T floats
    float* ll2 = lse + (size_t)BB * TT;        // B floats
    float* lossb = ll2 + BB;                   // B floats

    hipLaunchKernelGGL(fused_kernel, dim3(BB + LSE_BLOCKS), dim3(256), 0, stream,
                       in, tg, lse, ll2);
    hipLaunchKernelGGL(bsum_kernel, dim3(BB), dim3(256), 0, stream, lse, ll2, lossb);
    hipLaunchKernelGGL(final_kernel, dim3(1), dim3(64), 0, stream, lossb, out);
}

// Round 5
// 341.288 us; speedup vs baseline: 1.6491x; 1.1597x over previous
//
#include <hip/hip_runtime.h>

#define BB 128
#define TT 3000
#define CC 64
#define LL 128
// S = 2L+1 = 257
#define NEG (-1e30f)
#define LOG2E 1.4426950408889634f
#define LN2f 0.6931471805599453f
#define CH 15                 // frames per register chunk; 3000 = 200 * 15
#define NCHUNK 200
#define LSE_BLOCKS 1024       // extra blocks doing the softmax-normalizer pass

__device__ __forceinline__ float fexp2(float x) { return __builtin_amdgcn_exp2f(x); }
__device__ __forceinline__ float flog2(float x) { return __builtin_amdgcn_logf(x); }

// base-2 logsumexp of two base-2 log-domain values (6 VALU)
__device__ __forceinline__ float lse2(float x, float y) {
    float m = fmaxf(x, y);
    float e = fexp2(-fabsf(x - y));          // v_exp_f32 with -|.| src modifier
    return m + flog2(1.0f + e);
}
// lane l gets lane l-1's value (lane 0 gets NEG) via DPP wave_shr:1 — VALU speed
__device__ __forceinline__ float shr1_neg(float x) {
    int r = __builtin_amdgcn_update_dpp(__float_as_int(NEG), __float_as_int(x),
                                        0x138 /*wave_shr:1*/, 0xF, 0xF, false);
    return __int_as_float(r);
}
#define SBAR() __builtin_amdgcn_sched_barrier(0)

// Fused kernel.
// Blocks 0..BB-1 : CTC forward scan for batch b (1 wave; emissions gathered from
//                  global into double-buffered register arrays; sched_barrier
//                  fences stop the compiler from sinking the gathers into the
//                  serial chain — verify via VGPR_Count ~110+).
// Blocks BB..    : per-(b,t)-row softmax normalizer on otherwise-idle CUs.
__global__ __launch_bounds__(256) void fused_kernel(const float* __restrict__ in,
                                                    const int* __restrict__ tgt,
                                                    float* __restrict__ lse,
                                                    float* __restrict__ ll2) {
    if (blockIdx.x < BB) {
        if (threadIdx.x >= 64) return;       // scan uses wave 0 only
        __builtin_amdgcn_s_setprio(1);       // protect issue slots from lse waves
        int b = blockIdx.x;
        int lane = threadIdx.x;
        const float* fb = in + (size_t)b * TT * CC;
        int t0 = tgt[b * LL + 2 * lane];     // channel for odd state 4l+1
        int t1 = tgt[b * LL + 2 * lane + 1]; // channel for odd state 4l+3

        // double-buffered per-chunk emission registers (static indices only)
        float eA1[CH], eA3[CH], eAB[CH];
        float eB1[CH], eB3[CH], eBB[CH];

        // virtual pre-t=0 state: one uniform step then produces correct alpha_0
        float a0 = (lane == 0) ? 0.f : NEG;
        float a1 = NEG, a2 = NEG, a3 = NEG, a4 = NEG;

#define LOADC(S, c) { const float* bp = fb + (size_t)(c) * CH * CC;              \
        _Pragma("unroll") for (int j = 0; j < CH; ++j) {                         \
            e##S##1[j] = bp[j * CC + t0];                                        \
            e##S##3[j] = bp[j * CC + t1];                                        \
            e##S##B[j] = bp[j * CC + 63]; } }

        // shared-lse2 step: lse3(x,y,z) == lse2(x, lse2(y,z)); inner nodes reused
#define STEPC(S) {                                                               \
        _Pragma("unroll") for (int j = 0; j < CH; ++j) {                         \
            float emB = e##S##B[j] * LOG2E;                                      \
            float em1 = e##S##1[j] * LOG2E;                                      \
            float em3 = e##S##3[j] * LOG2E;                                      \
            float p3 = shr1_neg(a3);                                             \
            float t_ = lse2(a0, p3);                                             \
            float n0 = emB + t_;                                                 \
            float n1 = em1 + lse2(a1, t_);                                       \
            float u_ = lse2(a2, a1);                                             \
            float n2 = emB + u_;                                                 \
            float n3 = em3 + lse2(a3, u_);                                       \
            float n4 = emB + lse2(a4, a3);                                       \
            a0 = n0; a1 = n1; a2 = n2; a3 = n3; a4 = n4; } }

        LOADC(A, 0); SBAR();
        for (int c = 0; c < NCHUNK - 2; c += 2) {
            LOADC(B, c + 1); SBAR();   // issue next chunk's gathers, pinned here
            STEPC(A); SBAR();          // compute current chunk from registers
            LOADC(A, c + 2); SBAR();
            STEPC(B); SBAR();
        }
        LOADC(B, NCHUNK - 1); SBAR();
        STEPC(A); SBAR();              // chunk 198
        STEPC(B);                      // chunk 199
        // accepting states 255 (lane63 a3) and 256 (lane63 a4)
        if (lane == 63) ll2[b] = lse2(a3, a4);
        return;
    }
    // ---- softmax normalizer: one wave per (b,t) row, grid-strided ----
    int w = (blockIdx.x - BB) * 4 + (threadIdx.x >> 6);
    int lane = threadIdx.x & 63;
    const int stride = LSE_BLOCKS * 4;
    for (int row = w; row < BB * TT; row += stride) {
        float x = in[(size_t)row * CC + lane];
        float m = x;
        #pragma unroll
        for (int d = 32; d >= 1; d >>= 1) m = fmaxf(m, __shfl_xor(m, d, 64));
        float s = fexp2((x - m) * LOG2E);
        #pragma unroll
        for (int d = 32; d >= 1; d >>= 1) s += __shfl_xor(s, d, 64);
        if (lane == 0) lse[row] = m + flog2(s) * LN2f;
    }
}

// per-batch loss_b = sum_t lse_nat[b,t] - ll2[b]*ln2
__global__ __launch_bounds__(256) void bsum_kernel(const float* __restrict__ lse,
                                                   const float* __restrict__ ll2,
                                                   float* __restrict__ lossb) {
    __shared__ float red[256];
    int b = blockIdx.x;
    float s = 0.f;
    for (int i = threadIdx.x; i < TT; i += 256) s += lse[(size_t)b * TT + i];
    red[threadIdx.x] = s;
    __syncthreads();
    #pragma unroll
    for (int w = 128; w >= 1; w >>= 1) {
        if (threadIdx.x < w) red[threadIdx.x] += red[threadIdx.x + w];
        __syncthreads();
    }
    if (threadIdx.x == 0) lossb[b] = red[0] - ll2[b] * LN2f;
}

// mean over batch
__global__ __launch_bounds__(64) void final_kernel(const float* __restrict__ lossb,
                                                   float* __restrict__ out) {
    int lane = threadIdx.x;
    float v = lossb[lane] + lossb[lane + 64];
    #pragma unroll
    for (int d = 32; d >= 1; d >>= 1) v += __shfl_xor(v, d, 64);
    if (lane == 0) out[0] = v / (float)BB;
}

extern "C" void kernel_launch(void* const* d_in, const int* in_sizes, int n_in,
                              void* d_out, int out_size, void* d_ws, size_t ws_size,
                              hipStream_t stream) {
    const float* in = (const float*)d_in[0];
    const int* tg = (const int*)d_in[1];
    float* out = (float*)d_out;
    float* lse = (float*)d_ws;                 // B*T floats
    float* ll2 = lse + (size_t)BB * TT;        // B floats
    float* lossb = ll2 + BB;                   // B floats

    hipLaunchKernelGGL(fused_kernel, dim3(BB + LSE_BLOCKS), dim3(256), 0, stream,
                       in, tg, lse, ll2);
    hipLaunchKernelGGL(bsum_kernel, dim3(BB), dim3(256), 0, stream, lse, ll2, lossb);
    hipLaunchKernelGGL(final_kernel, dim3(1), dim3(64), 0, stream, lossb, out);
}